// Round 2
// baseline (146.167 us; speedup 1.0000x reference)
//
#include <hip/hip_runtime.h>
#include <math.h>

#define EPS 1e-5f

// ---------------------------------------------------------------------------
// Kernel 1: edge-conv (6->64) + BN + ReLU + max over K=520, fused with
//           conv2 (64->128) + BN + ReLU.  One block per (b, n).
// h = concat([ips - x, x]) so conv1 = W[:,0:3]*ips + ((W[:,3:6]-W[:,0:3])*x + b)
// BN folded into the 3 coeffs + bias.  max_k relu(v) = max(0, max_k v).
// blockIdx = n*256 + b  =>  all 15 n-blocks of one b are ≡ b (mod 8): same XCD,
// so the 12B-of-180B strided reads of info[b,:,n,:] share L2 lines per XCD.
// ---------------------------------------------------------------------------
__global__ __launch_bounds__(256) void k_stage12(
    const float* __restrict__ pts,        // [256,15,3]
    const float* __restrict__ info,       // [256,520,15,3]
    const float* __restrict__ w_info,     // [64,6]
    const float* __restrict__ b_info,
    const float* __restrict__ g_info, const float* __restrict__ be_info,
    const float* __restrict__ m_info, const float* __restrict__ v_info,
    const float* __restrict__ w2,         // [128,64]
    const float* __restrict__ b2,
    const float* __restrict__ g2, const float* __restrict__ be2,
    const float* __restrict__ m2, const float* __restrict__ v2,
    float* __restrict__ h2out)            // [256,15,128]
{
    __shared__ float4 ds[520];
    __shared__ float partial[4][64];
    __shared__ float h1s[64];

    const int tid = threadIdx.x;
    const int b = blockIdx.x & 255;       // XCD-locality swizzle
    const int n = blockIdx.x >> 8;

    const float x0 = pts[(b * 15 + n) * 3 + 0];
    const float x1 = pts[(b * 15 + n) * 3 + 1];
    const float x2 = pts[(b * 15 + n) * 3 + 2];

    // stage the 520 neighbor vectors for this (b,n): stride 45 floats
    const float* ib = info + ((size_t)b * 520 * 15 + n) * 3;
    for (int i = tid; i < 520; i += 256) {
        const float* p = ib + (size_t)i * 45;
        ds[i] = make_float4(p[0], p[1], p[2], 0.f);
    }

    // per-thread folded coefficients, o = tid & 63
    const int o = tid & 63;
    const float w0 = w_info[o * 6 + 0], w1 = w_info[o * 6 + 1], w2c = w_info[o * 6 + 2];
    const float w3 = w_info[o * 6 + 3], w4 = w_info[o * 6 + 4], w5 = w_info[o * 6 + 5];
    const float a  = g_info[o] * rsqrtf(v_info[o] + EPS);
    const float c0 = a * w0, c1 = a * w1, c2 = a * w2c;
    const float bias = a * ((w3 - w0) * x0 + (w4 - w1) * x1 + (w5 - w2c) * x2
                            + b_info[o] - m_info[o]) + be_info[o];

    __syncthreads();

    // wave w handles k in [w*130, w*130+130); lane = output channel o
    const int chunk = tid >> 6;
    const int k0 = chunk * 130;
    float acc = 0.f;   // relu floor
    #pragma unroll 2
    for (int k = k0; k < k0 + 130; ++k) {
        float4 d = ds[k];  // broadcast read (all lanes same address)
        float v = fmaf(c0, d.x, fmaf(c1, d.y, fmaf(c2, d.z, bias)));
        acc = fmaxf(acc, v);
    }
    partial[chunk][o] = acc;
    __syncthreads();

    if (tid < 64) {
        h1s[tid] = fmaxf(fmaxf(partial[0][tid], partial[1][tid]),
                         fmaxf(partial[2][tid], partial[3][tid]));
    }
    __syncthreads();

    // conv2: 64 -> 128, BN + ReLU
    if (tid < 128) {
        float accv = 0.f;
        const float* wr = w2 + tid * 64;
        #pragma unroll 16
        for (int c = 0; c < 64; ++c) accv = fmaf(wr[c], h1s[c], accv);
        const float a2 = g2[tid] * rsqrtf(v2[tid] + EPS);
        float val = a2 * (accv + b2[tid] - m2[tid]) + be2[tid];
        h2out[((size_t)b * 15 + n) * 128 + tid] = fmaxf(val, 0.f);
    }
}

// ---------------------------------------------------------------------------
// Kernel 2: conv3 (128->1024) + BN, then global max over N=15.
// One block per (b, 256-output quarter).  h2 row [15][128] staged in LDS.
// ---------------------------------------------------------------------------
__global__ __launch_bounds__(256) void k_stage3max(
    const float* __restrict__ h2,   // [256,15,128]
    const float* __restrict__ w3,   // [1024,128]
    const float* __restrict__ b3,
    const float* __restrict__ g3, const float* __restrict__ be3,
    const float* __restrict__ m3, const float* __restrict__ v3,
    float* __restrict__ gout)       // [256,1024]
{
    __shared__ float hs[15 * 128];
    const int tid = threadIdx.x;
    const int b = blockIdx.x >> 2;
    const int oq = blockIdx.x & 3;

    const float4* src = (const float4*)(h2 + (size_t)b * 1920);
    for (int i = tid; i < 480; i += 256) ((float4*)hs)[i] = src[i];
    __syncthreads();

    const int o = oq * 256 + tid;
    const float a3 = g3[o] * rsqrtf(v3[o] + EPS);
    const float bias = a3 * (b3[o] - m3[o]) + be3[o];

    float acc[15];
    #pragma unroll
    for (int n = 0; n < 15; ++n) acc[n] = 0.f;

    const float4* wr = (const float4*)(w3 + (size_t)o * 128);
    #pragma unroll 2
    for (int cq = 0; cq < 32; ++cq) {
        const float4 w = wr[cq];
        #pragma unroll
        for (int n = 0; n < 15; ++n) {
            const float4 h4 = *(const float4*)(hs + n * 128 + cq * 4); // broadcast
            acc[n] = fmaf(w.x, h4.x, fmaf(w.y, h4.y,
                     fmaf(w.z, h4.z, fmaf(w.w, h4.w, acc[n]))));
        }
    }
    float mx = -INFINITY;
    #pragma unroll
    for (int n = 0; n < 15; ++n) mx = fmaxf(mx, fmaf(a3, acc[n], bias));
    gout[(size_t)b * 1024 + o] = mx;
}

// ---------------------------------------------------------------------------
// FC GEMM: C[m][n] = act(sum_k A[m][k] * W[n][k] + ...)  (A row-major, W row-major)
// 32x32 tile, 256 threads, 2x2 micro-tile.  LDS pad 33 -> conflict-free reads.
// ---------------------------------------------------------------------------
template <bool BN_RELU>
__global__ __launch_bounds__(256) void k_fc(
    const float* __restrict__ A, const float* __restrict__ W,
    const float* __restrict__ bias,
    const float* __restrict__ gg, const float* __restrict__ be,
    const float* __restrict__ mm, const float* __restrict__ vv,
    float* __restrict__ C, int K, int Nc)
{
    __shared__ float As[32][33];
    __shared__ float Ws[32][33];

    const int tid = threadIdx.x;
    const int bm = blockIdx.x * 32, bn = blockIdx.y * 32;
    const int ml = (tid >> 4) * 2, nl = (tid & 15) * 2;
    const int row = tid >> 3, kq = (tid & 7) * 4;

    float acc00 = 0.f, acc01 = 0.f, acc10 = 0.f, acc11 = 0.f;

    for (int k0 = 0; k0 < K; k0 += 32) {
        const float4 av = *(const float4*)(A + (size_t)(bm + row) * K + k0 + kq);
        const float4 wv = *(const float4*)(W + (size_t)(bn + row) * K + k0 + kq);
        __syncthreads();
        As[row][kq + 0] = av.x; As[row][kq + 1] = av.y;
        As[row][kq + 2] = av.z; As[row][kq + 3] = av.w;
        Ws[row][kq + 0] = wv.x; Ws[row][kq + 1] = wv.y;
        Ws[row][kq + 2] = wv.z; Ws[row][kq + 3] = wv.w;
        __syncthreads();
        #pragma unroll
        for (int k = 0; k < 32; ++k) {
            const float a0 = As[ml][k], a1 = As[ml + 1][k];
            const float b0 = Ws[nl][k], b1 = Ws[nl + 1][k];
            acc00 = fmaf(a0, b0, acc00); acc01 = fmaf(a0, b1, acc01);
            acc10 = fmaf(a1, b0, acc10); acc11 = fmaf(a1, b1, acc11);
        }
    }

    const int n0 = bn + nl, n1 = n0 + 1;
    float v00, v01, v10, v11;
    if (BN_RELU) {
        const float s0 = gg[n0] * rsqrtf(vv[n0] + EPS);
        const float s1 = gg[n1] * rsqrtf(vv[n1] + EPS);
        const float c0 = s0 * (bias[n0] - mm[n0]) + be[n0];
        const float c1 = s1 * (bias[n1] - mm[n1]) + be[n1];
        v00 = fmaxf(fmaf(s0, acc00, c0), 0.f); v01 = fmaxf(fmaf(s1, acc01, c1), 0.f);
        v10 = fmaxf(fmaf(s0, acc10, c0), 0.f); v11 = fmaxf(fmaf(s1, acc11, c1), 0.f);
    } else {
        v00 = acc00 + bias[n0]; v01 = acc01 + bias[n1];
        v10 = acc10 + bias[n0]; v11 = acc11 + bias[n1];
    }
    float* cr0 = C + (size_t)(bm + ml) * Nc + n0;
    cr0[0] = v00; cr0[1] = v01;
    float* cr1 = C + (size_t)(bm + ml + 1) * Nc + n0;
    cr1[0] = v10; cr1[1] = v11;
}

// ---------------------------------------------------------------------------
extern "C" void kernel_launch(void* const* d_in, const int* in_sizes, int n_in,
                              void* d_out, int out_size, void* d_ws, size_t ws_size,
                              hipStream_t stream)
{
    const float* pts     = (const float*)d_in[0];
    // d_in[1] = label (unused)
    const float* info    = (const float*)d_in[2];
    const float* w_info  = (const float*)d_in[3];
    const float* b_info  = (const float*)d_in[4];
    const float* g_info  = (const float*)d_in[5];
    const float* be_info = (const float*)d_in[6];
    const float* m_info  = (const float*)d_in[7];
    const float* v_info  = (const float*)d_in[8];
    const float* w2      = (const float*)d_in[9];
    const float* b2      = (const float*)d_in[10];
    const float* g2      = (const float*)d_in[11];
    const float* be2     = (const float*)d_in[12];
    const float* m2      = (const float*)d_in[13];
    const float* v2      = (const float*)d_in[14];
    const float* w3      = (const float*)d_in[15];
    const float* b3      = (const float*)d_in[16];
    const float* g3      = (const float*)d_in[17];
    const float* be3     = (const float*)d_in[18];
    const float* m3      = (const float*)d_in[19];
    const float* v3      = (const float*)d_in[20];
    const float* wf1     = (const float*)d_in[21];
    const float* bf1     = (const float*)d_in[22];
    const float* gf1     = (const float*)d_in[23];
    const float* bef1    = (const float*)d_in[24];
    const float* mf1     = (const float*)d_in[25];
    const float* vf1     = (const float*)d_in[26];
    const float* wf2     = (const float*)d_in[27];
    const float* bf2     = (const float*)d_in[28];
    const float* gf2     = (const float*)d_in[29];
    const float* bef2    = (const float*)d_in[30];
    const float* mf2     = (const float*)d_in[31];
    const float* vf2     = (const float*)d_in[32];
    const float* wf3     = (const float*)d_in[33];
    const float* bf3     = (const float*)d_in[34];

    float* ws  = (float*)d_ws;
    float* h2  = ws;                       // 256*15*128 = 491520 floats
    float* g   = ws + 491520;              // 256*1024   = 262144 floats
    float* f1  = ws + 491520 + 262144;     // 256*512    = 131072 floats

    float* ret = (float*)d_out;            // [256, 800]
    float* f2  = ret + 256 * 800;          // [256, 256]

    k_stage12<<<15 * 256, 256, 0, stream>>>(
        pts, info, w_info, b_info, g_info, be_info, m_info, v_info,
        w2, b2, g2, be2, m2, v2, h2);

    k_stage3max<<<256 * 4, 256, 0, stream>>>(
        h2, w3, b3, g3, be3, m3, v3, g);

    k_fc<true><<<dim3(8, 16), 256, 0, stream>>>(
        g, wf1, bf1, gf1, bef1, mf1, vf1, f1, 1024, 512);

    k_fc<true><<<dim3(8, 8), 256, 0, stream>>>(
        f1, wf2, bf2, gf2, bef2, mf2, vf2, f2, 512, 256);

    k_fc<false><<<dim3(8, 25), 256, 0, stream>>>(
        f2, wf3, bf3, nullptr, nullptr, nullptr, nullptr, ret, 256, 800);
}